// Round 10
// baseline (169.247 us; speedup 1.0000x reference)
//
#include <hip/hip_runtime.h>
#include <hip/hip_bf16.h>
#include <cstdint>
#include <cstddef>

#define B_N   32
#define CIN_  128
#define COUT_ 128
#define KW_   7
#define L_    4096
#define NW_   256      // w-positions per block tile
#define NWELEM (KW_ * COUT_ * CIN_)   // 114688

#define SX_ROWS  264                  // 262 used (256 w + 6 taps); pad to 264
#define SX_ELEMS (SX_ROWS * CIN_)     // 33792 bf16 = 67584 B

typedef __attribute__((ext_vector_type(8))) short  bf16x8;
typedef __attribute__((ext_vector_type(4))) float  f32x4;

// Weight prep: ewb written directly in 16x16x32 MFMA A-fragment order.
// idx = (((t*8+og)*4+cc)*64 + li)*8 + e  holds
// exp(W[og*16+(li&15)][cc*32+(li>>4)*8+e]) at tap t, so tropconv loads a
// whole A-fragment as one coalesced 1KB wave read straight into VGPRs.
// (Layout correctness proven by R5/R6 passes.)
__global__ __launch_bounds__(256) void prep_w_kernel(
        const float* __restrict__ w, __hip_bfloat16* __restrict__ ewb) {
    int base = blockIdx.x * 1024 + threadIdx.x;
    #pragma unroll
    for (int i = 0; i < 4; ++i) {
        int idx = base + 256 * i;                   // 112 blocks cover 114688
        int e  = idx & 7;
        int li = (idx >> 3) & 63;
        int cc = (idx >> 9) & 3;
        int blk = idx >> 11;                        // 0..55
        int og = blk & 7, t = blk >> 3;
        int o  = og * 16 + (li & 15);
        int ch = cc * 32 + ((li >> 4) << 3) + e;
        ewb[idx] = __float2bfloat16(__expf(w[(o * CIN_ + ch) * KW_ + t]));
    }
}

// Fused conv GEMM, Round 10. exp_x + exT (100 MB HBM round-trip, ~20 us)
// deleted; the exp+transpose happens in-kernel via the PROVEN exp_x tile
// pattern, fixed where R6 went wrong:
//  - R6 spilled (40-deep staging loop): here staging is 9 compact chunks,
//    few live temporaries, all dead before acc is initialized.
//  - R6 scattered 2-byte writes into the full sX: here 2-byte writes go to
//    a small tileT[32][136] (exp_x's exact XOR layout, measured fine), and
//    sX is filled with b128 granule writes (conflict-benign).
// Chunked transpose: chunk k covers p-rows [32k, 32k+nr) of sX
// (p = l - w0 + 3). Load: lanes 0..15 read 9 aligned f32x4 granules of one
// channel row -> coalesced 144 B/row, 4 rows/wave-instr; exp; bf16; tileT.
// Barrier; transposed b128 read (exp_x read pattern) -> sX[p][slot] with
// slot = gc ^ (p&7) (R5 read-side invariant unchanged). Barrier. 9 chunks.
// Edge blocks: granules stay 4-aligned in x, so clamp keeps all-out
// granules all-out; per-element range test zero-fills (exp-space padding).
// LDS 67584 + 8704 = 76288 B -> 2 de-phased blocks/CU: one block's staging
// overlaps the other's compute/epilogue (the R5 TLP overlap, kept).
// Compute core + epilogue: byte-identical to R5 (the verified best).
__global__ __launch_bounds__(256, 2) void tropconv_kernel(
        const float* __restrict__ x,
        const __hip_bfloat16* __restrict__ ewb,
        const float* __restrict__ bias,
        float* __restrict__ out) {
    __shared__ __align__(16) __hip_bfloat16 sX[SX_ELEMS];      // 67584 B
    __shared__ __align__(16) __hip_bfloat16 tileT[32 * 136];   // 8704 B

    const int tid  = threadIdx.x;
    const int lane = tid & 63;
    const int wave = tid >> 6;
    const int wm   = wave >> 1;            // 0..1: o half (64 each)
    const int wn   = wave & 1;             // 0..1: w half (128 each)
    const int l15  = lane & 15;
    const int q    = lane >> 4;

    const int b  = blockIdx.y;
    const int w0 = blockIdx.x * NW_;
    const float* xb = x + (size_t)b * CIN_ * L_;

    // ---- fused staged transpose: 9 chunks of 32 p-rows.
    for (int k = 0; k < 9; ++k) {
        const int lo = k << 5;
        const int nr = (k == 8) ? 6 : 32;      // rows in this chunk
        // load/exp/convert into tileT[l_loc][c ^ swz]
        #pragma unroll
        for (int it = 0; it < 8; ++it) {
            int gid = tid + 256 * it;          // 0..2047
            int c   = gid >> 4;                // 0..127
            int gq  = gid & 15;                // granule slot; 9 used
            if (gq < 9) {
                int lx  = w0 - 4 + lo + (gq << 2);        // 4-aligned in x
                int lxc = min(max(lx, 0), L_ - 4);        // all-out stays all-out
                f32x4 v = *(const f32x4*)(xb + (size_t)c * L_ + lxc);
                #pragma unroll
                for (int e = 0; e < 4; ++e) {
                    int p  = lo + (gq << 2) + e - 1;      // = lx + e - w0 + 3
                    int pl = p - lo;
                    if ((unsigned)pl < (unsigned)nr) {
                        int lg = lx + e;
                        float val = ((unsigned)lg < (unsigned)L_) ? __expf(v[e]) : 0.0f;
                        int sw = (pl >> 2) & 15;
                        tileT[pl * 136 + (c ^ (sw << 3))] = __float2bfloat16(val);
                    }
                }
            }
        }
        __syncthreads();
        // transposed b128 read -> sX granules (slot = gc ^ (p&7))
        #pragma unroll
        for (int it = 0; it < 2; ++it) {
            int gid   = tid + 256 * it;        // 0..511
            int l_loc = gid >> 4;              // 0..31
            int gc    = gid & 15;              // channel granule
            if (l_loc < nr) {
                int sw = (l_loc >> 2) & 15;
                bf16x8 vv = *(const bf16x8*)&tileT[l_loc * 136 + ((gc ^ sw) << 3)];
                int p = lo + l_loc;
                *(bf16x8*)&sX[(p << 7) + ((gc ^ (p & 7)) << 3)] = vv;
            }
        }
        __syncthreads();                       // tileT reusable; sX chunk visible
    }

    f32x4 acc[4][8];
    #pragma unroll
    for (int i = 0; i < 4; ++i)
        #pragma unroll
        for (int j = 0; j < 8; ++j)
            acc[i][j] = (f32x4){0.f, 0.f, 0.f, 0.f};

    // A-frag (t,cc,mi): 1KB coalesced global load, lane li holds
    // W[og*16+(li&15)][cc*32+(li>>4)*8..+8], og = wm*4+mi.
#define ALOAD(AF, T, CC)                                                     \
    do {                                                                     \
        _Pragma("unroll")                                                    \
        for (int mi = 0; mi < 4; ++mi)                                       \
            AF[mi] = *(const bf16x8*)&ewb[(((((T) * 8 + wm * 4 + mi) * 4     \
                                             + (CC)) << 6) + lane) * 8];     \
    } while (0)

    // B-reads + 32 MFMAs for one (tap, chunk); b128 per lane, ~2/quad banks.
#define BDOT(AF, T, CC)                                                      \
    do {                                                                     \
        bf16x8 bx[8];                                                        \
        _Pragma("unroll")                                                    \
        for (int ni = 0; ni < 8; ++ni) {                                     \
            int p = wn * 128 + ni * 16 + l15 + (T);                          \
            int g = ((CC) * 4 + q) ^ (p & 7);                                \
            bx[ni] = *(const bf16x8*)&sX[(p << 7) + (g << 3)];               \
        }                                                                    \
        __builtin_amdgcn_s_setprio(1);                                       \
        _Pragma("unroll")                                                    \
        for (int mi = 0; mi < 4; ++mi)                                       \
            _Pragma("unroll")                                                \
            for (int ni = 0; ni < 8; ++ni)                                   \
                acc[mi][ni] = __builtin_amdgcn_mfma_f32_16x16x32_bf16(       \
                    AF[mi], bx[ni], acc[mi][ni], 0, 0, 0);                   \
        __builtin_amdgcn_s_setprio(0);                                       \
    } while (0)

    {
        bf16x8 afA[4], afB[4];
        ALOAD(afA, 0, 0);
        ALOAD(afB, 1, 0);  BDOT(afA, 0, 0);
        ALOAD(afA, 2, 0);  BDOT(afB, 1, 0);
        ALOAD(afB, 3, 0);  BDOT(afA, 2, 0);
        ALOAD(afA, 4, 0);  BDOT(afB, 3, 0);
        ALOAD(afB, 5, 0);  BDOT(afA, 4, 0);
        ALOAD(afA, 6, 0);  BDOT(afB, 5, 0);
        ALOAD(afB, 0, 1);  BDOT(afA, 6, 0);
        ALOAD(afA, 1, 1);  BDOT(afB, 0, 1);
        ALOAD(afB, 2, 1);  BDOT(afA, 1, 1);
        ALOAD(afA, 3, 1);  BDOT(afB, 2, 1);
        ALOAD(afB, 4, 1);  BDOT(afA, 3, 1);
        ALOAD(afA, 5, 1);  BDOT(afB, 4, 1);
        ALOAD(afB, 6, 1);  BDOT(afA, 5, 1);
        ALOAD(afA, 0, 2);  BDOT(afB, 6, 1);
        ALOAD(afB, 1, 2);  BDOT(afA, 0, 2);
        ALOAD(afA, 2, 2);  BDOT(afB, 1, 2);
        ALOAD(afB, 3, 2);  BDOT(afA, 2, 2);
        ALOAD(afA, 4, 2);  BDOT(afB, 3, 2);
        ALOAD(afB, 5, 2);  BDOT(afA, 4, 2);
        ALOAD(afA, 6, 2);  BDOT(afB, 5, 2);
        ALOAD(afB, 0, 3);  BDOT(afA, 6, 2);
        ALOAD(afA, 1, 3);  BDOT(afB, 0, 3);
        ALOAD(afB, 2, 3);  BDOT(afA, 1, 3);
        ALOAD(afA, 3, 3);  BDOT(afB, 2, 3);
        ALOAD(afB, 4, 3);  BDOT(afA, 3, 3);
        ALOAD(afA, 5, 3);  BDOT(afB, 4, 3);
        ALOAD(afB, 6, 3);  BDOT(afA, 5, 3);
                           BDOT(afB, 6, 3);
    }
#undef ALOAD
#undef BDOT

    // epilogue: y = log(s) + bias[o]; C/D: col=lane&15 (w), row=q*4+reg (cout)
    float* outb = out + (size_t)b * COUT_ * L_;
    #pragma unroll
    for (int mi = 0; mi < 4; ++mi) {
        #pragma unroll
        for (int r = 0; r < 4; ++r) {
            int o = wm * 64 + mi * 16 + q * 4 + r;
            float bv = bias[o];
            #pragma unroll
            for (int ni = 0; ni < 8; ++ni) {
                int w = w0 + wn * 128 + ni * 16 + l15;
                outb[(size_t)o * L_ + w] = __logf(acc[mi][ni][r]) + bv;
            }
        }
    }
}

extern "C" void kernel_launch(void* const* d_in, const int* in_sizes, int n_in,
                              void* d_out, int out_size, void* d_ws, size_t ws_size,
                              hipStream_t stream) {
    const float* x    = (const float*)d_in[0];   // (32,128,4096) f32
    const float* wgt  = (const float*)d_in[1];   // (128,128,7)   f32
    const float* bias = (const float*)d_in[2];   // (128,)        f32
    float* out = (float*)d_out;                  // (32,128,4096) f32

    // workspace: ewb only (229 KB) -- exT intermediate eliminated
    __hip_bfloat16* ewb = (__hip_bfloat16*)d_ws;

    prep_w_kernel<<<NWELEM / 1024, 256, 0, stream>>>(wgt, ewb);
    tropconv_kernel<<<dim3(L_ / NW_, B_N), 256, 0, stream>>>(x, ewb, bias, out);
}